// Round 1
// baseline (1880.093 us; speedup 1.0000x reference)
//
#include <hip/hip_runtime.h>

#define NN 100000
#define NE 1600000
constexpr float BN_EPS = 1e-5f;
constexpr float LRELU_SLOPE = 0.01f;

// ---------------------------------------------------------------- degree + col histogram
__global__ __launch_bounds__(256) void k_deg_cnt(const int* __restrict__ row,
                                                 const int* __restrict__ col,
                                                 int* __restrict__ deg,
                                                 int* __restrict__ cnt) {
  int e = blockIdx.x * 256 + threadIdx.x;
  if (e < NE) {
    atomicAdd(&deg[row[e]], 1);
    atomicAdd(&cnt[col[e]], 1);
  }
}

__global__ __launch_bounds__(256) void k_dinv(const int* __restrict__ deg,
                                              float* __restrict__ dinv) {
  int n = blockIdx.x * 256 + threadIdx.x;
  if (n < NN) {
    int d = deg[n];
    dinv[n] = d > 0 ? rsqrtf((float)d) : 0.0f;
  }
}

// ---------------------------------------------------------------- exclusive scan of col counts (1 block)
__global__ __launch_bounds__(1024) void k_scan(const int* __restrict__ cnt,
                                               int* __restrict__ ptr,
                                               int* __restrict__ cursor) {
  __shared__ int sh[1024];
  const int tid = threadIdx.x;
  const int CH = (NN + 1023) / 1024;  // 98
  const int base = tid * CH;
  int s = 0;
  for (int i = 0; i < CH; i++) {
    int idx = base + i;
    if (idx < NN) s += cnt[idx];
  }
  sh[tid] = s;
  __syncthreads();
  for (int off = 1; off < 1024; off <<= 1) {
    int v = (tid >= off) ? sh[tid - off] : 0;
    __syncthreads();
    sh[tid] += v;
    __syncthreads();
  }
  int run = sh[tid] - s;  // exclusive prefix
  for (int i = 0; i < CH; i++) {
    int idx = base + i;
    if (idx < NN) {
      ptr[idx] = run;
      cursor[idx] = run;
      run += cnt[idx];
    }
  }
  if (tid == 0) ptr[NN] = sh[1023];
}

// ---------------------------------------------------------------- CSR fill (sorted by destination col)
__global__ __launch_bounds__(256) void k_fill(const int* __restrict__ row,
                                              const int* __restrict__ col,
                                              const float* __restrict__ dinv,
                                              int* __restrict__ cursor,
                                              int* __restrict__ csrc,
                                              float* __restrict__ cw) {
  int e = blockIdx.x * 256 + threadIdx.x;
  if (e < NE) {
    int r = row[e], c = col[e];
    int pos = atomicAdd(&cursor[c], 1);
    csrc[pos] = r;
    cw[pos] = -dinv[r] * dinv[c];
  }
}

// ---------------------------------------------------------------- prop: y[n] = sum_{e: col=n} w_e * h[src_e]
template <int C>
__global__ __launch_bounds__(256) void k_prop(const float* __restrict__ h,
                                              const int* __restrict__ ptr,
                                              const int* __restrict__ src,
                                              const float* __restrict__ w,
                                              float* __restrict__ y) {
  constexpr int LPN = C / 4;       // lanes per node (float4 per lane)
  constexpr int NPB = 256 / LPN;   // nodes per block
  const int node = blockIdx.x * NPB + (int)(threadIdx.x / LPN);
  const int lane = threadIdx.x % LPN;
  if (node >= NN) return;
  const int b = ptr[node], e = ptr[node + 1];
  float4 acc = make_float4(0.f, 0.f, 0.f, 0.f);
  const float4* hp = reinterpret_cast<const float4*>(h) + lane;
  for (int j = b; j < e; j++) {
    int s = src[j];
    float wt = w[j];
    float4 hv = hp[(size_t)s * LPN];
    acc.x += wt * hv.x;
    acc.y += wt * hv.y;
    acc.z += wt * hv.z;
    acc.w += wt * hv.w;
  }
  reinterpret_cast<float4*>(y)[(size_t)node * LPN + lane] = acc;
}

// ---------------------------------------------------------------- conv: out = act@W0 + y@W1 + b
template <int Cin, int Cout>
__global__ __launch_bounds__(256) void k_conv(const float* __restrict__ act,
                                              const float* __restrict__ y,
                                              const float* __restrict__ W,
                                              const float* __restrict__ bias,
                                              float* __restrict__ out) {
  constexpr int NPB = 32;
  __shared__ float sA[NPB][Cin];
  __shared__ float sY[NPB][Cin];
  const int tid = threadIdx.x;
  const size_t blk0 = (size_t)blockIdx.x * NPB;
  constexpr int V4 = NPB * Cin / 4;
  const float4* a4 = reinterpret_cast<const float4*>(act + blk0 * Cin);
  const float4* y4 = reinterpret_cast<const float4*>(y + blk0 * Cin);
  float4* sA4 = reinterpret_cast<float4*>(&sA[0][0]);
  float4* sY4 = reinterpret_cast<float4*>(&sY[0][0]);
  for (int i = tid; i < V4; i += 256) {
    sA4[i] = a4[i];
    sY4[i] = y4[i];
  }
  __syncthreads();
  constexpr int PAIRS = Cout / 2;
  constexpr int G = 256 / PAIRS;  // node-groups in flight
  const int cp = tid % PAIRS;
  const int ng = tid / PAIRS;
  const float2* W0 = reinterpret_cast<const float2*>(W) + cp;
  const float2* W1 = reinterpret_cast<const float2*>(W + Cin * Cout) + cp;
  const float2 b2 = reinterpret_cast<const float2*>(bias)[cp];
  for (int p = 0; p < NPB / G; p++) {
    const int ln = p * G + ng;
    float acc0 = b2.x, acc1 = b2.y;
#pragma unroll 4
    for (int ci = 0; ci < Cin; ci++) {
      float a = sA[ln][ci];
      float yy = sY[ln][ci];
      float2 w0 = W0[ci * PAIRS];
      float2 w1 = W1[ci * PAIRS];
      acc0 += a * w0.x + yy * w1.x;
      acc1 += a * w0.y + yy * w1.y;
    }
    reinterpret_cast<float2*>(out + (blk0 + ln) * Cout)[cp] = make_float2(acc0, acc1);
  }
}

// ---------------------------------------------------------------- BN stats (per-channel sum / sumsq)
template <int C>
__global__ __launch_bounds__(256) void k_bnstats(const float* __restrict__ h,
                                                 float* __restrict__ bnsum,
                                                 float* __restrict__ bnsq) {
  constexpr int RPB = 256 / C;
  constexpr int ROWS = 256;
  const int c = threadIdx.x % C;
  const int g = threadIdx.x / C;
  const int r0 = blockIdx.x * ROWS + g;
  const int rend = min(blockIdx.x * ROWS + ROWS, NN);
  float s = 0.f, sq = 0.f;
  for (int r = r0; r < rend; r += RPB) {
    float v = h[(size_t)r * C + c];
    s += v;
    sq += v * v;
  }
  __shared__ float ss[256], sg[256];
  ss[threadIdx.x] = s;
  sg[threadIdx.x] = sq;
  __syncthreads();
  for (int st = 128; st >= C; st >>= 1) {
    if (threadIdx.x < st) {
      ss[threadIdx.x] += ss[threadIdx.x + st];
      sg[threadIdx.x] += sg[threadIdx.x + st];
    }
    __syncthreads();
  }
  if (threadIdx.x < C) {
    atomicAdd(&bnsum[threadIdx.x], ss[threadIdx.x]);
    atomicAdd(&bnsq[threadIdx.x], sg[threadIdx.x]);
  }
}

template <int C>
__global__ void k_bnfin(const float* __restrict__ bnsum, const float* __restrict__ bnsq,
                        const float* __restrict__ gamma, const float* __restrict__ beta,
                        float* __restrict__ scale, float* __restrict__ shift) {
  int c = threadIdx.x;
  if (c < C) {
    float mean = bnsum[c] * (1.0f / NN);
    float var = bnsq[c] * (1.0f / NN) - mean * mean;
    float sc = gamma[c] * rsqrtf(var + BN_EPS);
    scale[c] = sc;
    shift[c] = beta[c] - mean * sc;
  }
}

// ---------------------------------------------------------------- BN affine + LeakyReLU, in place
template <int C>
__global__ __launch_bounds__(256) void k_bnapply(float* __restrict__ h,
                                                 const float* __restrict__ scale,
                                                 const float* __restrict__ shift) {
  size_t i = (size_t)blockIdx.x * 256 + threadIdx.x;  // float4 index, grid sized exactly
  int cb = (int)((i * 4) % C);
  float4 v = reinterpret_cast<float4*>(h)[i];
  float4 sc = *reinterpret_cast<const float4*>(scale + cb);
  float4 sh = *reinterpret_cast<const float4*>(shift + cb);
  float4 o;
  o.x = sc.x * v.x + sh.x;
  o.y = sc.y * v.y + sh.y;
  o.z = sc.z * v.z + sh.z;
  o.w = sc.w * v.w + sh.w;
  o.x = o.x >= 0.f ? o.x : LRELU_SLOPE * o.x;
  o.y = o.y >= 0.f ? o.y : LRELU_SLOPE * o.y;
  o.z = o.z >= 0.f ? o.z : LRELU_SLOPE * o.z;
  o.w = o.w >= 0.f ? o.w : LRELU_SLOPE * o.w;
  reinterpret_cast<float4*>(h)[i] = o;
}

// ----------------------------------------------------------------
extern "C" void kernel_launch(void* const* d_in, const int* in_sizes, int n_in,
                              void* d_out, int out_size, void* d_ws, size_t ws_size,
                              hipStream_t stream) {
  const float* x   = (const float*)d_in[0];
  const int*   ei  = (const int*)d_in[1];
  const int*   row = ei;
  const int*   col = ei + NE;
  const float* W1  = (const float*)d_in[2];
  const float* b1  = (const float*)d_in[3];
  const float* W2  = (const float*)d_in[4];
  const float* b2  = (const float*)d_in[5];
  const float* W3  = (const float*)d_in[6];
  const float* b3  = (const float*)d_in[7];
  const float* g1  = (const float*)d_in[8];
  const float* be1 = (const float*)d_in[9];
  const float* g2  = (const float*)d_in[10];
  const float* be2 = (const float*)d_in[11];
  float* out = (float*)d_out;

  char* ws = (char*)d_ws;
  size_t off = 0;
  auto alloc = [&](size_t bytes) -> void* {
    void* p = ws + off;
    off = (off + bytes + 255) & ~(size_t)255;
    return p;
  };

  // --- zeroed region (one memset) ---
  int*   deg    = (int*)alloc(NN * 4);
  int*   cnt    = (int*)alloc(NN * 4);
  float* bnsum1 = (float*)alloc(128 * 4);
  float* bnsq1  = (float*)alloc(128 * 4);
  float* bnsum2 = (float*)alloc(64 * 4);
  float* bnsq2  = (float*)alloc(64 * 4);
  const size_t zero_bytes = off;
  // --- rest ---
  float* dinv   = (float*)alloc(NN * 4);
  int*   ptr    = (int*)alloc((NN + 1) * 4);
  int*   cursor = (int*)alloc(NN * 4);
  int*   csrc   = (int*)alloc((size_t)NE * 4);
  float* cw     = (float*)alloc((size_t)NE * 4);
  float* scale1 = (float*)alloc(128 * 4);
  float* shift1 = (float*)alloc(128 * 4);
  float* scale2 = (float*)alloc(64 * 4);
  float* shift2 = (float*)alloc(64 * 4);
  float* ybuf   = (float*)alloc((size_t)NN * 128 * 4);
  float* h1     = (float*)alloc((size_t)NN * 128 * 4);
  float* h2     = (float*)alloc((size_t)NN * 64 * 4);

  hipMemsetAsync(d_ws, 0, zero_bytes, stream);

  // graph prep
  k_deg_cnt<<<NE / 256, 256, 0, stream>>>(row, col, deg, cnt);
  k_dinv<<<(NN + 255) / 256, 256, 0, stream>>>(deg, dinv);
  k_scan<<<1, 1024, 0, stream>>>(cnt, ptr, cursor);
  k_fill<<<NE / 256, 256, 0, stream>>>(row, col, dinv, cursor, csrc, cw);

  // layer 1: 64 -> 128, BN + lrelu
  k_prop<64><<<NN / 16, 256, 0, stream>>>(x, ptr, csrc, cw, ybuf);
  k_conv<64, 128><<<NN / 32, 256, 0, stream>>>(x, ybuf, W1, b1, h1);
  k_bnstats<128><<<(NN + 255) / 256, 256, 0, stream>>>(h1, bnsum1, bnsq1);
  k_bnfin<128><<<1, 128, 0, stream>>>(bnsum1, bnsq1, g1, be1, scale1, shift1);
  k_bnapply<128><<<NN * 128 / 4 / 256, 256, 0, stream>>>(h1, scale1, shift1);

  // layer 2: 128 -> 64, BN + lrelu
  k_prop<128><<<NN / 8, 256, 0, stream>>>(h1, ptr, csrc, cw, ybuf);
  k_conv<128, 64><<<NN / 32, 256, 0, stream>>>(h1, ybuf, W2, b2, h2);
  k_bnstats<64><<<(NN + 255) / 256, 256, 0, stream>>>(h2, bnsum2, bnsq2);
  k_bnfin<64><<<1, 64, 0, stream>>>(bnsum2, bnsq2, g2, be2, scale2, shift2);
  k_bnapply<64><<<NN * 64 / 4 / 256, 256, 0, stream>>>(h2, scale2, shift2);

  // layer 3: 64 -> 64, no BN
  k_prop<64><<<NN / 16, 256, 0, stream>>>(h2, ptr, csrc, cw, ybuf);
  k_conv<64, 64><<<NN / 32, 256, 0, stream>>>(h2, ybuf, W3, b3, out);
}

// Round 2
// 1225.293 us; speedup vs baseline: 1.5344x; 1.5344x over previous
//
#include <hip/hip_runtime.h>

#define NN 100000
#define NE 1600000
constexpr float BN_EPS = 1e-5f;
constexpr float LRELU_SLOPE = 0.01f;

// ---------------------------------------------------------------- degree + col histogram
__global__ __launch_bounds__(256) void k_deg_cnt(const int* __restrict__ row,
                                                 const int* __restrict__ col,
                                                 int* __restrict__ deg,
                                                 int* __restrict__ cnt) {
  int e = blockIdx.x * 256 + threadIdx.x;
  if (e < NE) {
    atomicAdd(&deg[row[e]], 1);
    atomicAdd(&cnt[col[e]], 1);
  }
}

__global__ __launch_bounds__(256) void k_dinv(const int* __restrict__ deg,
                                              float* __restrict__ dinv) {
  int n = blockIdx.x * 256 + threadIdx.x;
  if (n < NN) {
    int d = deg[n];
    dinv[n] = d > 0 ? rsqrtf((float)d) : 0.0f;
  }
}

// ---------------------------------------------------------------- exclusive scan of col counts (1 block)
__global__ __launch_bounds__(1024) void k_scan(const int* __restrict__ cnt,
                                               int* __restrict__ ptr,
                                               int* __restrict__ cursor) {
  __shared__ int sh[1024];
  const int tid = threadIdx.x;
  const int CH = (NN + 1023) / 1024;  // 98
  const int base = tid * CH;
  int s = 0;
  for (int i = 0; i < CH; i++) {
    int idx = base + i;
    if (idx < NN) s += cnt[idx];
  }
  sh[tid] = s;
  __syncthreads();
  for (int off = 1; off < 1024; off <<= 1) {
    int v = (tid >= off) ? sh[tid - off] : 0;
    __syncthreads();
    sh[tid] += v;
    __syncthreads();
  }
  int run = sh[tid] - s;  // exclusive prefix
  for (int i = 0; i < CH; i++) {
    int idx = base + i;
    if (idx < NN) {
      ptr[idx] = run;
      cursor[idx] = run;
      run += cnt[idx];
    }
  }
  if (tid == 0) ptr[NN] = sh[1023];
}

// ---------------------------------------------------------------- CSR fill (sorted by destination col)
__global__ __launch_bounds__(256) void k_fill(const int* __restrict__ row,
                                              const int* __restrict__ col,
                                              const float* __restrict__ dinv,
                                              int* __restrict__ cursor,
                                              int* __restrict__ csrc,
                                              float* __restrict__ cw) {
  int e = blockIdx.x * 256 + threadIdx.x;
  if (e < NE) {
    int r = row[e], c = col[e];
    int pos = atomicAdd(&cursor[c], 1);
    csrc[pos] = r;
    cw[pos] = -dinv[r] * dinv[c];
  }
}

// ---------------------------------------------------------------- prop: y[n] = sum_{e: col=n} w_e * h[src_e]
template <int C>
__global__ __launch_bounds__(256) void k_prop(const float* __restrict__ h,
                                              const int* __restrict__ ptr,
                                              const int* __restrict__ src,
                                              const float* __restrict__ w,
                                              float* __restrict__ y) {
  constexpr int LPN = C / 4;       // lanes per node (float4 per lane)
  constexpr int NPB = 256 / LPN;   // nodes per block
  const int node = blockIdx.x * NPB + (int)(threadIdx.x / LPN);
  const int lane = threadIdx.x % LPN;
  if (node >= NN) return;
  const int b = ptr[node], e = ptr[node + 1];
  float4 acc = make_float4(0.f, 0.f, 0.f, 0.f);
  const float4* hp = reinterpret_cast<const float4*>(h) + lane;
  for (int j = b; j < e; j++) {
    int s = src[j];
    float wt = w[j];
    float4 hv = hp[(size_t)s * LPN];
    acc.x += wt * hv.x;
    acc.y += wt * hv.y;
    acc.z += wt * hv.z;
    acc.w += wt * hv.w;
  }
  reinterpret_cast<float4*>(y)[(size_t)node * LPN + lane] = acc;
}

// ---------------------------------------------------------------- conv: out = act@W0 + y@W1 + b
// Register-tiled GEMM. BM=128 nodes/block, 256 threads = 16 node-groups x 16 cout-groups.
// Per-thread tile: 8 nodes x CW couts (CW = Cout/16). A,Y staged in LDS transposed [k][node],
// XOR-swizzled on node bits 3..4 by (k>>3)&3 so staging writes are 2-way (free) and frag
// reads conflict-free. W streamed from global (L1-resident row reuse across waves).
template <int Cin, int Cout>
__global__ __launch_bounds__(256, 2) void k_conv(const float* __restrict__ act,
                                                 const float* __restrict__ y,
                                                 const float* __restrict__ W,
                                                 const float* __restrict__ bias,
                                                 float* __restrict__ out) {
  constexpr int KC = 64;            // k-chunk per pass
  constexpr int KP = Cin / KC;      // 1 or 2 passes
  constexpr int BM = 128;           // nodes per block
  constexpr int LDN = BM + 4;       // padded row (132 floats)
  constexpr int CW = Cout / 16;     // couts per thread (8 or 4)
  __shared__ float SA[KC][LDN];
  __shared__ float SY[KC][LDN];
  const int tid = threadIdx.x;
  const int cg = tid & 15;          // cout group
  const int ng = tid >> 4;          // node group
  const int n0 = blockIdx.x * BM;

  float acc[8][CW];
#pragma unroll
  for (int i = 0; i < 8; i++)
#pragma unroll
    for (int j = 0; j < CW; j++) acc[i][j] = 0.f;

  const float* Wg0 = W;                  // [Cin][Cout]
  const float* Wg1 = W + Cin * Cout;

  for (int kp = 0; kp < KP; kp++) {
    if (kp) __syncthreads();
    // stage: transpose [node][k] -> [k][node] with swizzle
    for (int idx = tid; idx < BM * (KC / 4); idx += 256) {
      const int n = idx >> 4;            // 0..127
      const int k4 = idx & 15;           // 0..15
      int node = n0 + n;
      if (node >= NN) node = NN - 1;
      const size_t gb = (size_t)node * Cin + kp * KC + k4 * 4;
      const float4 av = *reinterpret_cast<const float4*>(&act[gb]);
      const float4 yv = *reinterpret_cast<const float4*>(&y[gb]);
      const int ns = n ^ (((k4 >> 1) & 3) << 3);   // swizzle: k>>3 == k4>>1
      SA[k4 * 4 + 0][ns] = av.x; SA[k4 * 4 + 1][ns] = av.y;
      SA[k4 * 4 + 2][ns] = av.z; SA[k4 * 4 + 3][ns] = av.w;
      SY[k4 * 4 + 0][ns] = yv.x; SY[k4 * 4 + 1][ns] = yv.y;
      SY[k4 * 4 + 2][ns] = yv.z; SY[k4 * 4 + 3][ns] = yv.w;
    }
    __syncthreads();
    const float* w0p = Wg0 + (size_t)(kp * KC) * Cout + cg * CW;
    const float* w1p = Wg1 + (size_t)(kp * KC) * Cout + cg * CW;
#pragma unroll 8
    for (int k = 0; k < KC; k++) {
      const int nb = (ng * 8) ^ (((k >> 3) & 3) << 3);
      float a[8], yy[8], w0[CW], w1[CW];
      *reinterpret_cast<float4*>(&a[0])  = *reinterpret_cast<const float4*>(&SA[k][nb]);
      *reinterpret_cast<float4*>(&a[4])  = *reinterpret_cast<const float4*>(&SA[k][nb + 4]);
      *reinterpret_cast<float4*>(&yy[0]) = *reinterpret_cast<const float4*>(&SY[k][nb]);
      *reinterpret_cast<float4*>(&yy[4]) = *reinterpret_cast<const float4*>(&SY[k][nb + 4]);
#pragma unroll
      for (int j = 0; j < CW; j += 4) {
        *reinterpret_cast<float4*>(&w0[j]) = *reinterpret_cast<const float4*>(&w0p[k * Cout + j]);
        *reinterpret_cast<float4*>(&w1[j]) = *reinterpret_cast<const float4*>(&w1p[k * Cout + j]);
      }
#pragma unroll
      for (int i = 0; i < 8; i++)
#pragma unroll
        for (int j = 0; j < CW; j++)
          acc[i][j] += a[i] * w0[j] + yy[i] * w1[j];
    }
  }
  // epilogue: + bias, store
  float bv[CW];
#pragma unroll
  for (int j = 0; j < CW; j++) bv[j] = bias[cg * CW + j];
#pragma unroll
  for (int i = 0; i < 8; i++) {
    const int node = n0 + ng * 8 + i;
    if (node < NN) {
#pragma unroll
      for (int j = 0; j < CW; j += 4) {
        float4 o = make_float4(acc[i][j] + bv[j], acc[i][j + 1] + bv[j + 1],
                               acc[i][j + 2] + bv[j + 2], acc[i][j + 3] + bv[j + 3]);
        *reinterpret_cast<float4*>(&out[(size_t)node * Cout + cg * CW + j]) = o;
      }
    }
  }
}

// ---------------------------------------------------------------- BN stats (per-channel sum / sumsq)
template <int C>
__global__ __launch_bounds__(256) void k_bnstats(const float* __restrict__ h,
                                                 float* __restrict__ bnsum,
                                                 float* __restrict__ bnsq) {
  constexpr int RPB = 256 / C;
  constexpr int ROWS = 256;
  const int c = threadIdx.x % C;
  const int g = threadIdx.x / C;
  const int r0 = blockIdx.x * ROWS + g;
  const int rend = min(blockIdx.x * ROWS + ROWS, NN);
  float s = 0.f, sq = 0.f;
  for (int r = r0; r < rend; r += RPB) {
    float v = h[(size_t)r * C + c];
    s += v;
    sq += v * v;
  }
  __shared__ float ss[256], sg[256];
  ss[threadIdx.x] = s;
  sg[threadIdx.x] = sq;
  __syncthreads();
  for (int st = 128; st >= C; st >>= 1) {
    if (threadIdx.x < st) {
      ss[threadIdx.x] += ss[threadIdx.x + st];
      sg[threadIdx.x] += sg[threadIdx.x + st];
    }
    __syncthreads();
  }
  if (threadIdx.x < C) {
    atomicAdd(&bnsum[threadIdx.x], ss[threadIdx.x]);
    atomicAdd(&bnsq[threadIdx.x], sg[threadIdx.x]);
  }
}

template <int C>
__global__ void k_bnfin(const float* __restrict__ bnsum, const float* __restrict__ bnsq,
                        const float* __restrict__ gamma, const float* __restrict__ beta,
                        float* __restrict__ scale, float* __restrict__ shift) {
  int c = threadIdx.x;
  if (c < C) {
    float mean = bnsum[c] * (1.0f / NN);
    float var = bnsq[c] * (1.0f / NN) - mean * mean;
    float sc = gamma[c] * rsqrtf(var + BN_EPS);
    scale[c] = sc;
    shift[c] = beta[c] - mean * sc;
  }
}

// ---------------------------------------------------------------- BN affine + LeakyReLU, in place
template <int C>
__global__ __launch_bounds__(256) void k_bnapply(float* __restrict__ h,
                                                 const float* __restrict__ scale,
                                                 const float* __restrict__ shift) {
  size_t i = (size_t)blockIdx.x * 256 + threadIdx.x;  // float4 index, grid sized exactly
  int cb = (int)((i * 4) % C);
  float4 v = reinterpret_cast<float4*>(h)[i];
  float4 sc = *reinterpret_cast<const float4*>(scale + cb);
  float4 sh = *reinterpret_cast<const float4*>(shift + cb);
  float4 o;
  o.x = sc.x * v.x + sh.x;
  o.y = sc.y * v.y + sh.y;
  o.z = sc.z * v.z + sh.z;
  o.w = sc.w * v.w + sh.w;
  o.x = o.x >= 0.f ? o.x : LRELU_SLOPE * o.x;
  o.y = o.y >= 0.f ? o.y : LRELU_SLOPE * o.y;
  o.z = o.z >= 0.f ? o.z : LRELU_SLOPE * o.z;
  o.w = o.w >= 0.f ? o.w : LRELU_SLOPE * o.w;
  reinterpret_cast<float4*>(h)[i] = o;
}

// ----------------------------------------------------------------
extern "C" void kernel_launch(void* const* d_in, const int* in_sizes, int n_in,
                              void* d_out, int out_size, void* d_ws, size_t ws_size,
                              hipStream_t stream) {
  const float* x   = (const float*)d_in[0];
  const int*   ei  = (const int*)d_in[1];
  const int*   row = ei;
  const int*   col = ei + NE;
  const float* W1  = (const float*)d_in[2];
  const float* b1  = (const float*)d_in[3];
  const float* W2  = (const float*)d_in[4];
  const float* b2  = (const float*)d_in[5];
  const float* W3  = (const float*)d_in[6];
  const float* b3  = (const float*)d_in[7];
  const float* g1  = (const float*)d_in[8];
  const float* be1 = (const float*)d_in[9];
  const float* g2  = (const float*)d_in[10];
  const float* be2 = (const float*)d_in[11];
  float* out = (float*)d_out;

  char* ws = (char*)d_ws;
  size_t off = 0;
  auto alloc = [&](size_t bytes) -> void* {
    void* p = ws + off;
    off = (off + bytes + 255) & ~(size_t)255;
    return p;
  };

  // --- zeroed region (one memset) ---
  int*   deg    = (int*)alloc(NN * 4);
  int*   cnt    = (int*)alloc(NN * 4);
  float* bnsum1 = (float*)alloc(128 * 4);
  float* bnsq1  = (float*)alloc(128 * 4);
  float* bnsum2 = (float*)alloc(64 * 4);
  float* bnsq2  = (float*)alloc(64 * 4);
  const size_t zero_bytes = off;
  // --- rest ---
  float* dinv   = (float*)alloc(NN * 4);
  int*   ptr    = (int*)alloc((NN + 1) * 4);
  int*   cursor = (int*)alloc(NN * 4);
  int*   csrc   = (int*)alloc((size_t)NE * 4);
  float* cw     = (float*)alloc((size_t)NE * 4);
  float* scale1 = (float*)alloc(128 * 4);
  float* shift1 = (float*)alloc(128 * 4);
  float* scale2 = (float*)alloc(64 * 4);
  float* shift2 = (float*)alloc(64 * 4);
  float* ybuf   = (float*)alloc((size_t)NN * 128 * 4);
  float* h1     = (float*)alloc((size_t)NN * 128 * 4);
  float* h2     = (float*)alloc((size_t)NN * 64 * 4);

  hipMemsetAsync(d_ws, 0, zero_bytes, stream);

  // graph prep
  k_deg_cnt<<<NE / 256, 256, 0, stream>>>(row, col, deg, cnt);
  k_dinv<<<(NN + 255) / 256, 256, 0, stream>>>(deg, dinv);
  k_scan<<<1, 1024, 0, stream>>>(cnt, ptr, cursor);
  k_fill<<<NE / 256, 256, 0, stream>>>(row, col, dinv, cursor, csrc, cw);

  const int convGrid = (NN + 127) / 128;

  // layer 1: 64 -> 128, BN + lrelu
  k_prop<64><<<NN / 16, 256, 0, stream>>>(x, ptr, csrc, cw, ybuf);
  k_conv<64, 128><<<convGrid, 256, 0, stream>>>(x, ybuf, W1, b1, h1);
  k_bnstats<128><<<(NN + 255) / 256, 256, 0, stream>>>(h1, bnsum1, bnsq1);
  k_bnfin<128><<<1, 128, 0, stream>>>(bnsum1, bnsq1, g1, be1, scale1, shift1);
  k_bnapply<128><<<NN * 128 / 4 / 256, 256, 0, stream>>>(h1, scale1, shift1);

  // layer 2: 128 -> 64, BN + lrelu
  k_prop<128><<<NN / 8, 256, 0, stream>>>(h1, ptr, csrc, cw, ybuf);
  k_conv<128, 64><<<convGrid, 256, 0, stream>>>(h1, ybuf, W2, b2, h2);
  k_bnstats<64><<<(NN + 255) / 256, 256, 0, stream>>>(h2, bnsum2, bnsq2);
  k_bnfin<64><<<1, 64, 0, stream>>>(bnsum2, bnsq2, g2, be2, scale2, shift2);
  k_bnapply<64><<<NN * 64 / 4 / 256, 256, 0, stream>>>(h2, scale2, shift2);

  // layer 3: 64 -> 64, no BN
  k_prop<64><<<NN / 16, 256, 0, stream>>>(h2, ptr, csrc, cw, ybuf);
  k_conv<64, 64><<<convGrid, 256, 0, stream>>>(h2, ybuf, W3, b3, out);
}

// Round 3
// 921.906 us; speedup vs baseline: 2.0394x; 1.3291x over previous
//
#include <hip/hip_runtime.h>

#define NN 100000
#define NE 1600000
constexpr float BN_EPS = 1e-5f;
constexpr float LRELU_SLOPE = 0.01f;
constexpr int SC_NB = (NN + 255) / 256;  // 391 scan blocks

// ---------------------------------------------------------------- degree + col histogram
__global__ __launch_bounds__(256) void k_deg_cnt(const int* __restrict__ row,
                                                 const int* __restrict__ col,
                                                 int* __restrict__ deg,
                                                 int* __restrict__ cnt) {
  int e = blockIdx.x * 256 + threadIdx.x;
  if (e < NE) {
    atomicAdd(&deg[row[e]], 1);
    atomicAdd(&cnt[col[e]], 1);
  }
}

__global__ __launch_bounds__(256) void k_dinv(const int* __restrict__ deg,
                                              float* __restrict__ dinv) {
  int n = blockIdx.x * 256 + threadIdx.x;
  if (n < NN) {
    int d = deg[n];
    dinv[n] = d > 0 ? rsqrtf((float)d) : 0.0f;
  }
}

// ---------------------------------------------------------------- 3-phase exclusive scan of cnt
__global__ __launch_bounds__(256) void k_scan_a(const int* __restrict__ cnt,
                                                int* __restrict__ bsum) {
  __shared__ int sh[256];
  const int tid = threadIdx.x;
  const int i = blockIdx.x * 256 + tid;
  sh[tid] = (i < NN) ? cnt[i] : 0;
  __syncthreads();
  for (int st = 128; st > 0; st >>= 1) {
    if (tid < st) sh[tid] += sh[tid + st];
    __syncthreads();
  }
  if (tid == 0) bsum[blockIdx.x] = sh[0];
}

__global__ __launch_bounds__(512) void k_scan_b(const int* __restrict__ bsum,
                                                int* __restrict__ boff) {
  __shared__ int sh[512];
  const int tid = threadIdx.x;
  const int v = (tid < SC_NB) ? bsum[tid] : 0;
  sh[tid] = v;
  __syncthreads();
  for (int off = 1; off < 512; off <<= 1) {
    int t = (tid >= off) ? sh[tid - off] : 0;
    __syncthreads();
    sh[tid] += t;
    __syncthreads();
  }
  if (tid < SC_NB) boff[tid] = sh[tid] - v;  // exclusive
}

__global__ __launch_bounds__(256) void k_scan_c(const int* __restrict__ cnt,
                                                const int* __restrict__ boff,
                                                int* __restrict__ ptr,
                                                int* __restrict__ cursor) {
  __shared__ int sh[256];
  const int tid = threadIdx.x;
  const int i = blockIdx.x * 256 + tid;
  const int v = (i < NN) ? cnt[i] : 0;
  sh[tid] = v;
  __syncthreads();
  for (int off = 1; off < 256; off <<= 1) {
    int t = (tid >= off) ? sh[tid - off] : 0;
    __syncthreads();
    sh[tid] += t;
    __syncthreads();
  }
  const int excl = sh[tid] - v + boff[blockIdx.x];
  if (i < NN) {
    ptr[i] = excl;
    cursor[i] = excl;
    if (i == NN - 1) ptr[NN] = excl + v;
  }
}

// ---------------------------------------------------------------- CSR fill (sorted by destination col)
__global__ __launch_bounds__(256) void k_fill(const int* __restrict__ row,
                                              const int* __restrict__ col,
                                              const float* __restrict__ dinv,
                                              int* __restrict__ cursor,
                                              int* __restrict__ csrc,
                                              float* __restrict__ cw) {
  int e = blockIdx.x * 256 + threadIdx.x;
  if (e < NE) {
    int r = row[e], c = col[e];
    int pos = atomicAdd(&cursor[c], 1);
    csrc[pos] = r;
    cw[pos] = -dinv[r] * dinv[c];
  }
}

// ---------------------------------------------------------------- prop: y[n] = sum_{e: col=n} w_e * h[src_e]
// Unrolled x2: two independent gathers in flight per thread (latency-bound loop).
template <int C>
__global__ __launch_bounds__(256) void k_prop(const float* __restrict__ h,
                                              const int* __restrict__ ptr,
                                              const int* __restrict__ src,
                                              const float* __restrict__ w,
                                              float* __restrict__ y) {
  constexpr int LPN = C / 4;       // lanes per node (float4 per lane)
  constexpr int NPB = 256 / LPN;   // nodes per block
  const int node = blockIdx.x * NPB + (int)(threadIdx.x / LPN);
  const int lane = threadIdx.x % LPN;
  if (node >= NN) return;
  const int b = ptr[node], e = ptr[node + 1];
  float4 acc0 = make_float4(0.f, 0.f, 0.f, 0.f);
  float4 acc1 = make_float4(0.f, 0.f, 0.f, 0.f);
  const float4* hp = reinterpret_cast<const float4*>(h) + lane;
  int j = b;
  for (; j + 2 <= e; j += 2) {
    const int s0 = src[j], s1 = src[j + 1];
    const float w0 = w[j], w1 = w[j + 1];
    const float4 h0 = hp[(size_t)s0 * LPN];
    const float4 h1 = hp[(size_t)s1 * LPN];
    acc0.x += w0 * h0.x; acc0.y += w0 * h0.y; acc0.z += w0 * h0.z; acc0.w += w0 * h0.w;
    acc1.x += w1 * h1.x; acc1.y += w1 * h1.y; acc1.z += w1 * h1.z; acc1.w += w1 * h1.w;
  }
  if (j < e) {
    const int s0 = src[j];
    const float w0 = w[j];
    const float4 h0 = hp[(size_t)s0 * LPN];
    acc0.x += w0 * h0.x; acc0.y += w0 * h0.y; acc0.z += w0 * h0.z; acc0.w += w0 * h0.w;
  }
  acc0.x += acc1.x; acc0.y += acc1.y; acc0.z += acc1.z; acc0.w += acc1.w;
  reinterpret_cast<float4*>(y)[(size_t)node * LPN + lane] = acc0;
}

// ---------------------------------------------------------------- conv: out = act@W0 + y@W1 + b
// Register-tiled GEMM. BM=128 nodes/block, 256 threads = 16 node-groups x 16 cout-groups.
template <int Cin, int Cout>
__global__ __launch_bounds__(256, 2) void k_conv(const float* __restrict__ act,
                                                 const float* __restrict__ y,
                                                 const float* __restrict__ W,
                                                 const float* __restrict__ bias,
                                                 float* __restrict__ out) {
  constexpr int KC = 64;            // k-chunk per pass
  constexpr int KP = Cin / KC;      // 1 or 2 passes
  constexpr int BM = 128;           // nodes per block
  constexpr int LDN = BM + 4;       // padded row (132 floats)
  constexpr int CW = Cout / 16;     // couts per thread (8 or 4)
  __shared__ float SA[KC][LDN];
  __shared__ float SY[KC][LDN];
  const int tid = threadIdx.x;
  const int cg = tid & 15;          // cout group
  const int ng = tid >> 4;          // node group
  const int n0 = blockIdx.x * BM;

  float acc[8][CW];
#pragma unroll
  for (int i = 0; i < 8; i++)
#pragma unroll
    for (int j = 0; j < CW; j++) acc[i][j] = 0.f;

  const float* Wg0 = W;                  // [Cin][Cout]
  const float* Wg1 = W + Cin * Cout;

  for (int kp = 0; kp < KP; kp++) {
    if (kp) __syncthreads();
    // stage: transpose [node][k] -> [k][node] with swizzle
    for (int idx = tid; idx < BM * (KC / 4); idx += 256) {
      const int n = idx >> 4;            // 0..127
      const int k4 = idx & 15;           // 0..15
      int node = n0 + n;
      if (node >= NN) node = NN - 1;
      const size_t gb = (size_t)node * Cin + kp * KC + k4 * 4;
      const float4 av = *reinterpret_cast<const float4*>(&act[gb]);
      const float4 yv = *reinterpret_cast<const float4*>(&y[gb]);
      const int ns = n ^ (((k4 >> 1) & 3) << 3);   // swizzle: k>>3 == k4>>1
      SA[k4 * 4 + 0][ns] = av.x; SA[k4 * 4 + 1][ns] = av.y;
      SA[k4 * 4 + 2][ns] = av.z; SA[k4 * 4 + 3][ns] = av.w;
      SY[k4 * 4 + 0][ns] = yv.x; SY[k4 * 4 + 1][ns] = yv.y;
      SY[k4 * 4 + 2][ns] = yv.z; SY[k4 * 4 + 3][ns] = yv.w;
    }
    __syncthreads();
    const float* w0p = Wg0 + (size_t)(kp * KC) * Cout + cg * CW;
    const float* w1p = Wg1 + (size_t)(kp * KC) * Cout + cg * CW;
#pragma unroll 8
    for (int k = 0; k < KC; k++) {
      const int nb = (ng * 8) ^ (((k >> 3) & 3) << 3);
      float a[8], yy[8], w0[CW], w1[CW];
      *reinterpret_cast<float4*>(&a[0])  = *reinterpret_cast<const float4*>(&SA[k][nb]);
      *reinterpret_cast<float4*>(&a[4])  = *reinterpret_cast<const float4*>(&SA[k][nb + 4]);
      *reinterpret_cast<float4*>(&yy[0]) = *reinterpret_cast<const float4*>(&SY[k][nb]);
      *reinterpret_cast<float4*>(&yy[4]) = *reinterpret_cast<const float4*>(&SY[k][nb + 4]);
#pragma unroll
      for (int j = 0; j < CW; j += 4) {
        *reinterpret_cast<float4*>(&w0[j]) = *reinterpret_cast<const float4*>(&w0p[k * Cout + j]);
        *reinterpret_cast<float4*>(&w1[j]) = *reinterpret_cast<const float4*>(&w1p[k * Cout + j]);
      }
#pragma unroll
      for (int i = 0; i < 8; i++)
#pragma unroll
        for (int j = 0; j < CW; j++)
          acc[i][j] += a[i] * w0[j] + yy[i] * w1[j];
    }
  }
  // epilogue: + bias, store
  float bv[CW];
#pragma unroll
  for (int j = 0; j < CW; j++) bv[j] = bias[cg * CW + j];
#pragma unroll
  for (int i = 0; i < 8; i++) {
    const int node = n0 + ng * 8 + i;
    if (node < NN) {
#pragma unroll
      for (int j = 0; j < CW; j += 4) {
        float4 o = make_float4(acc[i][j] + bv[j], acc[i][j + 1] + bv[j + 1],
                               acc[i][j + 2] + bv[j + 2], acc[i][j + 3] + bv[j + 3]);
        *reinterpret_cast<float4*>(&out[(size_t)node * Cout + cg * CW + j]) = o;
      }
    }
  }
}

// ---------------------------------------------------------------- BN stats (per-channel sum / sumsq)
template <int C>
__global__ __launch_bounds__(256) void k_bnstats(const float* __restrict__ h,
                                                 float* __restrict__ bnsum,
                                                 float* __restrict__ bnsq) {
  constexpr int RPB = 256 / C;
  constexpr int ROWS = 256;
  const int c = threadIdx.x % C;
  const int g = threadIdx.x / C;
  const int r0 = blockIdx.x * ROWS + g;
  const int rend = min(blockIdx.x * ROWS + ROWS, NN);
  float s = 0.f, sq = 0.f;
  for (int r = r0; r < rend; r += RPB) {
    float v = h[(size_t)r * C + c];
    s += v;
    sq += v * v;
  }
  __shared__ float ss[256], sg[256];
  ss[threadIdx.x] = s;
  sg[threadIdx.x] = sq;
  __syncthreads();
  for (int st = 128; st >= C; st >>= 1) {
    if (threadIdx.x < st) {
      ss[threadIdx.x] += ss[threadIdx.x + st];
      sg[threadIdx.x] += sg[threadIdx.x + st];
    }
    __syncthreads();
  }
  if (threadIdx.x < C) {
    atomicAdd(&bnsum[threadIdx.x], ss[threadIdx.x]);
    atomicAdd(&bnsq[threadIdx.x], sg[threadIdx.x]);
  }
}

template <int C>
__global__ void k_bnfin(const float* __restrict__ bnsum, const float* __restrict__ bnsq,
                        const float* __restrict__ gamma, const float* __restrict__ beta,
                        float* __restrict__ scale, float* __restrict__ shift) {
  int c = threadIdx.x;
  if (c < C) {
    float mean = bnsum[c] * (1.0f / NN);
    float var = bnsq[c] * (1.0f / NN) - mean * mean;
    float sc = gamma[c] * rsqrtf(var + BN_EPS);
    scale[c] = sc;
    shift[c] = beta[c] - mean * sc;
  }
}

// ---------------------------------------------------------------- BN affine + LeakyReLU, in place
template <int C>
__global__ __launch_bounds__(256) void k_bnapply(float* __restrict__ h,
                                                 const float* __restrict__ scale,
                                                 const float* __restrict__ shift) {
  size_t i = (size_t)blockIdx.x * 256 + threadIdx.x;  // float4 index, grid sized exactly
  int cb = (int)((i * 4) % C);
  float4 v = reinterpret_cast<float4*>(h)[i];
  float4 sc = *reinterpret_cast<const float4*>(scale + cb);
  float4 sh = *reinterpret_cast<const float4*>(shift + cb);
  float4 o;
  o.x = sc.x * v.x + sh.x;
  o.y = sc.y * v.y + sh.y;
  o.z = sc.z * v.z + sh.z;
  o.w = sc.w * v.w + sh.w;
  o.x = o.x >= 0.f ? o.x : LRELU_SLOPE * o.x;
  o.y = o.y >= 0.f ? o.y : LRELU_SLOPE * o.y;
  o.z = o.z >= 0.f ? o.z : LRELU_SLOPE * o.z;
  o.w = o.w >= 0.f ? o.w : LRELU_SLOPE * o.w;
  reinterpret_cast<float4*>(h)[i] = o;
}

// ----------------------------------------------------------------
extern "C" void kernel_launch(void* const* d_in, const int* in_sizes, int n_in,
                              void* d_out, int out_size, void* d_ws, size_t ws_size,
                              hipStream_t stream) {
  const float* x   = (const float*)d_in[0];
  const int*   ei  = (const int*)d_in[1];
  const int*   row = ei;
  const int*   col = ei + NE;
  const float* W1  = (const float*)d_in[2];
  const float* b1  = (const float*)d_in[3];
  const float* W2  = (const float*)d_in[4];
  const float* b2  = (const float*)d_in[5];
  const float* W3  = (const float*)d_in[6];
  const float* b3  = (const float*)d_in[7];
  const float* g1  = (const float*)d_in[8];
  const float* be1 = (const float*)d_in[9];
  const float* g2  = (const float*)d_in[10];
  const float* be2 = (const float*)d_in[11];
  float* out = (float*)d_out;

  char* ws = (char*)d_ws;
  size_t off = 0;
  auto alloc = [&](size_t bytes) -> void* {
    void* p = ws + off;
    off = (off + bytes + 255) & ~(size_t)255;
    return p;
  };

  // --- zeroed region (one memset) ---
  int*   deg    = (int*)alloc(NN * 4);
  int*   cnt    = (int*)alloc(NN * 4);
  float* bnsum1 = (float*)alloc(128 * 4);
  float* bnsq1  = (float*)alloc(128 * 4);
  float* bnsum2 = (float*)alloc(64 * 4);
  float* bnsq2  = (float*)alloc(64 * 4);
  const size_t zero_bytes = off;
  // --- rest ---
  float* dinv   = (float*)alloc(NN * 4);
  int*   ptr    = (int*)alloc((NN + 1) * 4);
  int*   cursor = (int*)alloc(NN * 4);
  int*   bsum   = (int*)alloc(SC_NB * 4);
  int*   boff   = (int*)alloc(SC_NB * 4);
  int*   csrc   = (int*)alloc((size_t)NE * 4);
  float* cw     = (float*)alloc((size_t)NE * 4);
  float* scale1 = (float*)alloc(128 * 4);
  float* shift1 = (float*)alloc(128 * 4);
  float* scale2 = (float*)alloc(64 * 4);
  float* shift2 = (float*)alloc(64 * 4);
  float* ybuf   = (float*)alloc((size_t)NN * 128 * 4);
  float* h1     = (float*)alloc((size_t)NN * 128 * 4);
  float* h2     = (float*)alloc((size_t)NN * 64 * 4);

  hipMemsetAsync(d_ws, 0, zero_bytes, stream);

  // graph prep
  k_deg_cnt<<<NE / 256, 256, 0, stream>>>(row, col, deg, cnt);
  k_dinv<<<(NN + 255) / 256, 256, 0, stream>>>(deg, dinv);
  k_scan_a<<<SC_NB, 256, 0, stream>>>(cnt, bsum);
  k_scan_b<<<1, 512, 0, stream>>>(bsum, boff);
  k_scan_c<<<SC_NB, 256, 0, stream>>>(cnt, boff, ptr, cursor);
  k_fill<<<NE / 256, 256, 0, stream>>>(row, col, dinv, cursor, csrc, cw);

  const int convGrid = (NN + 127) / 128;

  // layer 1: 64 -> 128, BN + lrelu
  k_prop<64><<<NN / 16, 256, 0, stream>>>(x, ptr, csrc, cw, ybuf);
  k_conv<64, 128><<<convGrid, 256, 0, stream>>>(x, ybuf, W1, b1, h1);
  k_bnstats<128><<<(NN + 255) / 256, 256, 0, stream>>>(h1, bnsum1, bnsq1);
  k_bnfin<128><<<1, 128, 0, stream>>>(bnsum1, bnsq1, g1, be1, scale1, shift1);
  k_bnapply<128><<<NN * 128 / 4 / 256, 256, 0, stream>>>(h1, scale1, shift1);

  // layer 2: 128 -> 64, BN + lrelu
  k_prop<128><<<NN / 8, 256, 0, stream>>>(h1, ptr, csrc, cw, ybuf);
  k_conv<128, 64><<<convGrid, 256, 0, stream>>>(h1, ybuf, W2, b2, h2);
  k_bnstats<64><<<(NN + 255) / 256, 256, 0, stream>>>(h2, bnsum2, bnsq2);
  k_bnfin<64><<<1, 64, 0, stream>>>(bnsum2, bnsq2, g2, be2, scale2, shift2);
  k_bnapply<64><<<NN * 64 / 4 / 256, 256, 0, stream>>>(h2, scale2, shift2);

  // layer 3: 64 -> 64, no BN
  k_prop<64><<<NN / 16, 256, 0, stream>>>(h2, ptr, csrc, cw, ybuf);
  k_conv<64, 64><<<convGrid, 256, 0, stream>>>(h2, ybuf, W3, b3, out);
}

// Round 4
// 727.340 us; speedup vs baseline: 2.5849x; 1.2675x over previous
//
#include <hip/hip_runtime.h>

#define NN 100000
#define NE 1600000
constexpr float BN_EPS = 1e-5f;
constexpr float LRELU_SLOPE = 0.01f;
constexpr int SC_NB = (NN + 255) / 256;  // 391 scan blocks

// ---------------------------------------------------------------- degree + col histogram
__global__ __launch_bounds__(256) void k_deg_cnt(const int* __restrict__ row,
                                                 const int* __restrict__ col,
                                                 int* __restrict__ deg,
                                                 int* __restrict__ cnt) {
  int e = blockIdx.x * 256 + threadIdx.x;
  if (e < NE) {
    atomicAdd(&deg[row[e]], 1);
    atomicAdd(&cnt[col[e]], 1);
  }
}

__global__ __launch_bounds__(256) void k_dinv(const int* __restrict__ deg,
                                              float* __restrict__ dinv) {
  int n = blockIdx.x * 256 + threadIdx.x;
  if (n < NN) {
    int d = deg[n];
    dinv[n] = d > 0 ? rsqrtf((float)d) : 0.0f;
  }
}

// ---------------------------------------------------------------- 3-phase exclusive scan of cnt
__global__ __launch_bounds__(256) void k_scan_a(const int* __restrict__ cnt,
                                                int* __restrict__ bsum) {
  __shared__ int sh[256];
  const int tid = threadIdx.x;
  const int i = blockIdx.x * 256 + tid;
  sh[tid] = (i < NN) ? cnt[i] : 0;
  __syncthreads();
  for (int st = 128; st > 0; st >>= 1) {
    if (tid < st) sh[tid] += sh[tid + st];
    __syncthreads();
  }
  if (tid == 0) bsum[blockIdx.x] = sh[0];
}

__global__ __launch_bounds__(512) void k_scan_b(const int* __restrict__ bsum,
                                                int* __restrict__ boff) {
  __shared__ int sh[512];
  const int tid = threadIdx.x;
  const int v = (tid < SC_NB) ? bsum[tid] : 0;
  sh[tid] = v;
  __syncthreads();
  for (int off = 1; off < 512; off <<= 1) {
    int t = (tid >= off) ? sh[tid - off] : 0;
    __syncthreads();
    sh[tid] += t;
    __syncthreads();
  }
  if (tid < SC_NB) boff[tid] = sh[tid] - v;  // exclusive
}

__global__ __launch_bounds__(256) void k_scan_c(const int* __restrict__ cnt,
                                                const int* __restrict__ boff,
                                                int* __restrict__ ptr,
                                                int* __restrict__ cursor) {
  __shared__ int sh[256];
  const int tid = threadIdx.x;
  const int i = blockIdx.x * 256 + tid;
  const int v = (i < NN) ? cnt[i] : 0;
  sh[tid] = v;
  __syncthreads();
  for (int off = 1; off < 256; off <<= 1) {
    int t = (tid >= off) ? sh[tid - off] : 0;
    __syncthreads();
    sh[tid] += t;
    __syncthreads();
  }
  const int excl = sh[tid] - v + boff[blockIdx.x];
  if (i < NN) {
    ptr[i] = excl;
    cursor[i] = excl;
    if (i == NN - 1) ptr[NN] = excl + v;
  }
}

// ---------------------------------------------------------------- CSR fill: int2 {src, bits(w)}
__global__ __launch_bounds__(256) void k_fill(const int* __restrict__ row,
                                              const int* __restrict__ col,
                                              const float* __restrict__ dinv,
                                              int* __restrict__ cursor,
                                              int2* __restrict__ eb) {
  int e = blockIdx.x * 256 + threadIdx.x;
  if (e < NE) {
    int r = row[e], c = col[e];
    int pos = atomicAdd(&cursor[c], 1);
    int2 rec;
    rec.x = r;
    rec.y = __float_as_int(-dinv[r] * dinv[c]);
    eb[pos] = rec;
  }
}

// ---------------------------------------------------------------- prop (C=64): out[n] = [g[n] +] sum w_e p[src_e]
template <bool ADD>
__global__ __launch_bounds__(256) void k_prop64(const float* __restrict__ p,
                                                const int2* __restrict__ eb,
                                                const int* __restrict__ ptr,
                                                const float* __restrict__ g,
                                                float* __restrict__ out) {
  const int node = blockIdx.x * 16 + (threadIdx.x >> 4);
  const int lane = threadIdx.x & 15;
  if (node >= NN) return;
  const int b = ptr[node], e = ptr[node + 1];
  float4 acc0 = make_float4(0.f, 0.f, 0.f, 0.f);
  float4 acc1 = make_float4(0.f, 0.f, 0.f, 0.f);
  const float4* hp = reinterpret_cast<const float4*>(p) + lane;
  int j = b;
  for (; j + 2 <= e; j += 2) {
    const int2 e0 = eb[j], e1 = eb[j + 1];
    const float w0 = __int_as_float(e0.y), w1 = __int_as_float(e1.y);
    const float4 h0 = hp[(size_t)e0.x * 16];
    const float4 h1 = hp[(size_t)e1.x * 16];
    acc0.x += w0 * h0.x; acc0.y += w0 * h0.y; acc0.z += w0 * h0.z; acc0.w += w0 * h0.w;
    acc1.x += w1 * h1.x; acc1.y += w1 * h1.y; acc1.z += w1 * h1.z; acc1.w += w1 * h1.w;
  }
  if (j < e) {
    const int2 e0 = eb[j];
    const float w0 = __int_as_float(e0.y);
    const float4 h0 = hp[(size_t)e0.x * 16];
    acc0.x += w0 * h0.x; acc0.y += w0 * h0.y; acc0.z += w0 * h0.z; acc0.w += w0 * h0.w;
  }
  acc0.x += acc1.x; acc0.y += acc1.y; acc0.z += acc1.z; acc0.w += acc1.w;
  if (ADD) {
    const float4 gv = reinterpret_cast<const float4*>(g)[(size_t)node * 16 + lane];
    acc0.x += gv.x; acc0.y += gv.y; acc0.z += gv.z; acc0.w += gv.w;
  }
  reinterpret_cast<float4*>(out)[(size_t)node * 16 + lane] = acc0;
}

// ---------------------------------------------------------------- layer-1 conv: h1 = x@W0 + y@W1 + b
// lane=node design: 64 nodes/block, 512 thr; A/Y in LDS [64][65] (bank=(lane+k)%32, free);
// W rows read from wave-uniform address -> s_load (scalar pipe, no VALU/LDS cost).
__global__ __launch_bounds__(512) void k_conv1(const float* __restrict__ x,
                                               const float* __restrict__ y,
                                               const float* __restrict__ W,
                                               const float* __restrict__ bias,
                                               float* __restrict__ out) {
  __shared__ float XA[64][65];
  __shared__ float XY[64][65];
  const int tid = threadIdx.x;
  const int lane = tid & 63;
  const int wv = __builtin_amdgcn_readfirstlane(tid >> 6);  // 0..7
  const int n0 = blockIdx.x * 64;
  for (int idx = tid; idx < 1024; idx += 512) {
    const int n = idx >> 4, k4 = idx & 15;
    int node = n0 + n;
    if (node >= NN) node = NN - 1;
    const float4 av = *reinterpret_cast<const float4*>(x + (size_t)node * 64 + k4 * 4);
    const float4 yv = *reinterpret_cast<const float4*>(y + (size_t)node * 64 + k4 * 4);
    float* da = &XA[n][k4 * 4];
    da[0] = av.x; da[1] = av.y; da[2] = av.z; da[3] = av.w;
    float* dy = &XY[n][k4 * 4];
    dy[0] = yv.x; dy[1] = yv.y; dy[2] = yv.z; dy[3] = yv.w;
  }
  __syncthreads();
  const int cw0 = wv * 16;
  const float* __restrict__ W0 = W + cw0;             // [64][128]
  const float* __restrict__ W1 = W + 64 * 128 + cw0;
  float acc[16];
#pragma unroll
  for (int j = 0; j < 16; j++) acc[j] = 0.f;
#pragma unroll 4
  for (int k = 0; k < 64; k++) {
    const float a = XA[lane][k];
    const float b = XY[lane][k];
#pragma unroll
    for (int j = 0; j < 16; j++)
      acc[j] += a * W0[(size_t)k * 128 + j] + b * W1[(size_t)k * 128 + j];
  }
  const int node = n0 + lane;
  if (node < NN) {
#pragma unroll
    for (int j = 0; j < 16; j += 4) {
      float4 o = make_float4(acc[j] + bias[cw0 + j], acc[j + 1] + bias[cw0 + j + 1],
                             acc[j + 2] + bias[cw0 + j + 2], acc[j + 3] + bias[cw0 + j + 3]);
      *reinterpret_cast<float4*>(out + (size_t)node * 128 + cw0 + j) = o;
    }
  }
}

// ---------------------------------------------------------------- dual GEMM: g = bn(h)@Wa + b, p = bn(h)@Wb
// BN+LeakyReLU fused into the staging read. Cout = 64 for both outputs.
template <int Cin>
__global__ __launch_bounds__(512) void k_gemm_dual(const float* __restrict__ h,
                                                   const float* __restrict__ W,
                                                   const float* __restrict__ bias,
                                                   const float* __restrict__ scale,
                                                   const float* __restrict__ shift,
                                                   float* __restrict__ g,
                                                   float* __restrict__ p) {
  __shared__ float XA[64][Cin + 1];
  const int tid = threadIdx.x;
  const int lane = tid & 63;
  const int wv = __builtin_amdgcn_readfirstlane(tid >> 6);  // 0..7
  const int n0 = blockIdx.x * 64;
  constexpr int C4 = Cin / 4;
  for (int idx = tid; idx < 64 * C4; idx += 512) {
    const int n = idx / C4, k4 = idx % C4;
    int node = n0 + n;
    if (node >= NN) node = NN - 1;
    float4 v = *reinterpret_cast<const float4*>(h + (size_t)node * Cin + k4 * 4);
    const float4 sc = *reinterpret_cast<const float4*>(scale + k4 * 4);
    const float4 sh = *reinterpret_cast<const float4*>(shift + k4 * 4);
    v.x = sc.x * v.x + sh.x; v.y = sc.y * v.y + sh.y;
    v.z = sc.z * v.z + sh.z; v.w = sc.w * v.w + sh.w;
    v.x = v.x >= 0.f ? v.x : LRELU_SLOPE * v.x;
    v.y = v.y >= 0.f ? v.y : LRELU_SLOPE * v.y;
    v.z = v.z >= 0.f ? v.z : LRELU_SLOPE * v.z;
    v.w = v.w >= 0.f ? v.w : LRELU_SLOPE * v.w;
    float* d = &XA[n][k4 * 4];
    d[0] = v.x; d[1] = v.y; d[2] = v.z; d[3] = v.w;
  }
  __syncthreads();
  const int cw0 = wv * 8;
  const float* __restrict__ Wa = W + cw0;              // [Cin][64]
  const float* __restrict__ Wb = W + Cin * 64 + cw0;
  float ag[8], ap[8];
#pragma unroll
  for (int j = 0; j < 8; j++) { ag[j] = 0.f; ap[j] = 0.f; }
#pragma unroll 4
  for (int k = 0; k < Cin; k++) {
    const float a = XA[lane][k];
#pragma unroll
    for (int j = 0; j < 8; j++) {
      ag[j] += a * Wa[(size_t)k * 64 + j];
      ap[j] += a * Wb[(size_t)k * 64 + j];
    }
  }
  const int node = n0 + lane;
  if (node < NN) {
#pragma unroll
    for (int j = 0; j < 8; j += 4) {
      float4 og = make_float4(ag[j] + bias[cw0 + j], ag[j + 1] + bias[cw0 + j + 1],
                              ag[j + 2] + bias[cw0 + j + 2], ag[j + 3] + bias[cw0 + j + 3]);
      *reinterpret_cast<float4*>(g + (size_t)node * 64 + cw0 + j) = og;
      float4 op = make_float4(ap[j], ap[j + 1], ap[j + 2], ap[j + 3]);
      *reinterpret_cast<float4*>(p + (size_t)node * 64 + cw0 + j) = op;
    }
  }
}

// ---------------------------------------------------------------- BN stats (per-channel sum / sumsq)
template <int C>
__global__ __launch_bounds__(256) void k_bnstats(const float* __restrict__ h,
                                                 float* __restrict__ bnsum,
                                                 float* __restrict__ bnsq) {
  constexpr int RPB = 256 / C;
  constexpr int ROWS = 256;
  const int c = threadIdx.x % C;
  const int g = threadIdx.x / C;
  const int r0 = blockIdx.x * ROWS + g;
  const int rend = min(blockIdx.x * ROWS + ROWS, NN);
  float s = 0.f, sq = 0.f;
  for (int r = r0; r < rend; r += RPB) {
    float v = h[(size_t)r * C + c];
    s += v;
    sq += v * v;
  }
  __shared__ float ss[256], sg[256];
  ss[threadIdx.x] = s;
  sg[threadIdx.x] = sq;
  __syncthreads();
  for (int st = 128; st >= C; st >>= 1) {
    if (threadIdx.x < st) {
      ss[threadIdx.x] += ss[threadIdx.x + st];
      sg[threadIdx.x] += sg[threadIdx.x + st];
    }
    __syncthreads();
  }
  if (threadIdx.x < C) {
    atomicAdd(&bnsum[threadIdx.x], ss[threadIdx.x]);
    atomicAdd(&bnsq[threadIdx.x], sg[threadIdx.x]);
  }
}

template <int C>
__global__ void k_bnfin(const float* __restrict__ bnsum, const float* __restrict__ bnsq,
                        const float* __restrict__ gamma, const float* __restrict__ beta,
                        float* __restrict__ scale, float* __restrict__ shift) {
  int c = threadIdx.x;
  if (c < C) {
    float mean = bnsum[c] * (1.0f / NN);
    float var = bnsq[c] * (1.0f / NN) - mean * mean;
    float sc = gamma[c] * rsqrtf(var + BN_EPS);
    scale[c] = sc;
    shift[c] = beta[c] - mean * sc;
  }
}

// ----------------------------------------------------------------
extern "C" void kernel_launch(void* const* d_in, const int* in_sizes, int n_in,
                              void* d_out, int out_size, void* d_ws, size_t ws_size,
                              hipStream_t stream) {
  const float* x   = (const float*)d_in[0];
  const int*   ei  = (const int*)d_in[1];
  const int*   row = ei;
  const int*   col = ei + NE;
  const float* W1  = (const float*)d_in[2];
  const float* b1  = (const float*)d_in[3];
  const float* W2  = (const float*)d_in[4];
  const float* b2  = (const float*)d_in[5];
  const float* W3  = (const float*)d_in[6];
  const float* b3  = (const float*)d_in[7];
  const float* g1  = (const float*)d_in[8];
  const float* be1 = (const float*)d_in[9];
  const float* g2w = (const float*)d_in[10];
  const float* be2 = (const float*)d_in[11];
  float* out = (float*)d_out;

  char* ws = (char*)d_ws;
  size_t off = 0;
  auto alloc = [&](size_t bytes) -> void* {
    void* p = ws + off;
    off = (off + bytes + 255) & ~(size_t)255;
    return p;
  };

  // --- zeroed region (one memset) ---
  int*   deg    = (int*)alloc(NN * 4);
  int*   cnt    = (int*)alloc(NN * 4);
  float* bnsum1 = (float*)alloc(128 * 4);
  float* bnsq1  = (float*)alloc(128 * 4);
  float* bnsum2 = (float*)alloc(64 * 4);
  float* bnsq2  = (float*)alloc(64 * 4);
  const size_t zero_bytes = off;
  // --- rest ---
  float* dinv   = (float*)alloc(NN * 4);
  int*   ptr    = (int*)alloc((NN + 1) * 4);
  int*   cursor = (int*)alloc(NN * 4);
  int*   bsum   = (int*)alloc(SC_NB * 4);
  int*   boff   = (int*)alloc(SC_NB * 4);
  int2*  eb     = (int2*)alloc((size_t)NE * 8);
  float* scale1 = (float*)alloc(128 * 4);
  float* shift1 = (float*)alloc(128 * 4);
  float* scale2 = (float*)alloc(64 * 4);
  float* shift2 = (float*)alloc(64 * 4);
  float* bufA   = (float*)alloc((size_t)NN * 64 * 4);   // y1, later g2
  float* bufB   = (float*)alloc((size_t)NN * 128 * 4);  // h1, later g3|p3
  float* bufC   = (float*)alloc((size_t)NN * 64 * 4);   // p2
  float* bufD   = (float*)alloc((size_t)NN * 64 * 4);   // h2

  float* y1 = bufA;
  float* h1 = bufB;
  float* gg2 = bufA;
  float* p2 = bufC;
  float* h2 = bufD;
  float* gg3 = bufB;
  float* p3 = bufB + (size_t)NN * 64;

  hipMemsetAsync(d_ws, 0, zero_bytes, stream);

  // graph prep
  k_deg_cnt<<<NE / 256, 256, 0, stream>>>(row, col, deg, cnt);
  k_dinv<<<(NN + 255) / 256, 256, 0, stream>>>(deg, dinv);
  k_scan_a<<<SC_NB, 256, 0, stream>>>(cnt, bsum);
  k_scan_b<<<1, 512, 0, stream>>>(bsum, boff);
  k_scan_c<<<SC_NB, 256, 0, stream>>>(cnt, boff, ptr, cursor);
  k_fill<<<NE / 256, 256, 0, stream>>>(row, col, dinv, cursor, eb);

  const int gemmGrid = (NN + 63) / 64;
  const int propGrid = (NN * 16 + 255) / 256;

  // layer 1: y1 = L^ x ; h1 = x@W1[0] + y1@W1[1] + b1
  k_prop64<false><<<propGrid, 256, 0, stream>>>(x, eb, ptr, nullptr, y1);
  k_conv1<<<gemmGrid, 512, 0, stream>>>(x, y1, W1, b1, h1);
  k_bnstats<128><<<(NN + 255) / 256, 256, 0, stream>>>(h1, bnsum1, bnsq1);
  k_bnfin<128><<<1, 128, 0, stream>>>(bnsum1, bnsq1, g1, be1, scale1, shift1);

  // layer 2 (BN+lrelu fused into staging): g2 = bn(h1)@W2[0]+b2, p2 = bn(h1)@W2[1]; h2 = g2 + L^ p2
  k_gemm_dual<128><<<gemmGrid, 512, 0, stream>>>(h1, W2, b2, scale1, shift1, gg2, p2);
  k_prop64<true><<<propGrid, 256, 0, stream>>>(p2, eb, ptr, gg2, h2);
  k_bnstats<64><<<(NN + 255) / 256, 256, 0, stream>>>(h2, bnsum2, bnsq2);
  k_bnfin<64><<<1, 64, 0, stream>>>(bnsum2, bnsq2, g2w, be2, scale2, shift2);

  // layer 3: g3 = bn(h2)@W3[0]+b3, p3 = bn(h2)@W3[1]; out = g3 + L^ p3
  k_gemm_dual<64><<<gemmGrid, 512, 0, stream>>>(h2, W3, b3, scale2, shift2, gg3, p3);
  k_prop64<true><<<propGrid, 256, 0, stream>>>(p3, eb, ptr, gg3, out);
}